// Round 8
// baseline (166.233 us; speedup 1.0000x reference)
//
#include <hip/hip_runtime.h>
#include <math.h>

#define BB 128
#define LL 720
#define CC 321
#define HH 128
#define PP 336
#define MM 512
#define LPAD 736  // 720 padded to multiple of 32

typedef __attribute__((ext_vector_type(8))) short bf16x8;
typedef __attribute__((ext_vector_type(4))) float f32x4;

__device__ __forceinline__ short f2bf(float x) {
  unsigned u = __builtin_bit_cast(unsigned, x);
  u = (u + 0x7FFFu + ((u >> 16) & 1u)) >> 16;
  return (short)u;
}

// load an 8-element bf16 MFMA fragment from global: elems 0..3 at p, 4..7 at p+16
__device__ __forceinline__ bf16x8 ldfrag(const short* p) {
  short4 a = *(const short4*)p;
  short4 b = *(const short4*)(p + 16);
  bf16x8 r;
  r[0] = a.x; r[1] = a.y; r[2] = a.z; r[3] = a.w;
  r[4] = b.x; r[5] = b.y; r[6] = b.z; r[7] = b.w;
  return r;
}

// Stage one 16B "fragment chunk" from global W row: 8B at g, 8B at g+16.
__device__ __forceinline__ int4 stage_chunk(const short* g) {
  int2 lo = *(const int2*)g;
  int2 hi = *(const int2*)(g + 16);
  int4 r;
  r.x = lo.x; r.y = lo.y; r.z = hi.x; r.w = hi.y;
  return r;
}

// Fragment read from padded LDS tile, rows of 40 shorts (80B), fragment-packed
// (gemm2 layout): 8 contiguous shorts at h*40 + lg*8 -> ds_read_b128.
__device__ __forceinline__ bf16x8 ldsfragP(const short* tile, int h, int lg) {
  return *(const bf16x8*)&tile[h * 40 + lg * 8];
}

// Fragment read from PLAIN-row LDS tile (gemm1 v4): row h holds shorts k=0..31
// at h*40; fragment (h,lg) = shorts {lg*4..+4} and {16+lg*4..+4} -> 2x ds_read_b64.
__device__ __forceinline__ bf16x8 ldsfragR(const short* tile, int h, int lg) {
  int2 lo = *(const int2*)&tile[h * 40 + lg * 4];
  int2 hi = *(const int2*)&tile[h * 40 + lg * 4 + 16];
  union { int2 v[2]; bf16x8 f; } u;
  u.v[0] = lo;
  u.v[1] = hi;
  return u.f;
}

// async global->LDS, 16 bytes per lane; lds ptr must be wave-uniform base
__device__ __forceinline__ void gload_lds16(const short* g, short* l) {
  __builtin_amdgcn_global_load_lds(
      (const __attribute__((address_space(1))) unsigned int*)g,
      (__attribute__((address_space(3))) unsigned int*)l, 16, 0, 0);
}

// ---------------------------------------------------------------------------
// Kernel 1: effective (smeared) weights -> bf16 [H][LPAD] (zero-padded tail).
// ---------------------------------------------------------------------------
__global__ void weff_kernel(const float* __restrict__ Ws1,
                            const float* __restrict__ Wt1,
                            short* __restrict__ WsT,
                            short* __restrict__ WtT) {
  int idx = blockIdx.x * 256 + threadIdx.x;
  if (idx >= HH * LPAD) return;
  int j = idx % LPAD, h = idx / LPAD;
  if (j >= LL) { WsT[idx] = 0; WtT[idx] = 0; return; }
  float ss = 0.f, st = 0.f;
  if (j == 0) {
    for (int l = 0; l <= 12; ++l) {
      float w = 13.f - (float)l;
      ss += w * Ws1[h * LL + l];
      st += w * Wt1[h * LL + l];
    }
  } else if (j == LL - 1) {
    for (int d = 0; d <= 12; ++d) {
      float w = 13.f - (float)d;
      ss += w * Ws1[h * LL + LL - 1 - d];
      st += w * Wt1[h * LL + LL - 1 - d];
    }
  } else {
    int lo = j - 12 < 0 ? 0 : j - 12;
    int hi = j + 12 > LL - 1 ? LL - 1 : j + 12;
    for (int l = lo; l <= hi; ++l) {
      ss += Ws1[h * LL + l];
      st += Wt1[h * LL + l];
    }
  }
  ss *= (1.f / 25.f);
  st *= (1.f / 25.f);
  WsT[idx] = f2bf(Ws1[h * LL + j] - ss);
  WtT[idx] = f2bf(st);
}

// ---------------------------------------------------------------------------
// Kernel 1b: build staged mem images for memenh (unchanged from round 7).
// ---------------------------------------------------------------------------
__global__ void memstage_kernel(const float* __restrict__ memS,
                                const float* __restrict__ memT,
                                short* __restrict__ stgS,
                                short* __restrict__ stgT) {
  int e = blockIdx.x * 256 + threadIdx.x;  // 0..32767
  int br = e >> 14;
  int s = e & 16383;
  const float* src = br ? memT : memS;
  short* dst = br ? stgT : stgS;
  int tt = s >> 11;                        // tile 0..7
  int c = s & 2047;
  int row = c >> 4, slot = c & 15;
  int sp = slot ^ (row & 7);
  int k = sp >> 2, lg = sp & 3;
  int ft = tt >> 1;
  short out[8];
  if ((tt & 1) == 0) {
    const float* r0 = src + (size_t)(ft * 128 + row) * 128 + k * 32 + lg * 4;
#pragma unroll
    for (int j = 0; j < 4; ++j) {
      out[j] = f2bf(r0[j]);
      out[j + 4] = f2bf(r0[16 + j]);
    }
  } else {
    int fbase = ft * 128 + k * 32 + lg * 4;
#pragma unroll
    for (int j = 0; j < 4; ++j) {
      out[j] = f2bf(src[(size_t)(fbase + j) * 128 + row]);
      out[j + 4] = f2bf(src[(size_t)(fbase + 16 + j) * 128 + row]);
    }
  }
  short4 a = make_short4(out[0], out[1], out[2], out[3]);
  short4 b = make_short4(out[4], out[5], out[6], out[7]);
  *(short4*)&dst[(size_t)s * 8] = a;
  *(short4*)&dst[(size_t)s * 8 + 4] = b;
}

// ---------------------------------------------------------------------------
// Kernel 1c: W2cat bf16 [336][512] (k<256 = seasonal, else trend) + bias sum.
// ---------------------------------------------------------------------------
__global__ void w2cvt_kernel(const float* __restrict__ Ws2,
                             const float* __restrict__ Wt2,
                             const float* __restrict__ bs2,
                             const float* __restrict__ bt2,
                             short* __restrict__ W2b, float* __restrict__ b2) {
  int i = blockIdx.x * 256 + threadIdx.x;
  if (i < PP) b2[i] = bs2[i] + bt2[i];
  if (i >= PP * 512) return;
  int p = i >> 9, k = i & 511;
  float v = (k < 256) ? Ws2[p * 256 + k] : Wt2[p * 256 + (k - 256)];
  W2b[i] = f2bf(v);
}

// ---------------------------------------------------------------------------
// Kernel 2 (v4): MFMA dual-branch GEMM1 + sigmoid, register-blocked n.
//   256 thr / 4 waves; wave = 32 n x 64 h x 2 branches (ngrp = w>>1,
//   hhalf = w&1); block = 64 n x 128 h; grid 642.
//   A-frag reads feed 2 MFMAs each; W staged plain-row via coalesced
//   dwordx4; x gathered per-lane 1 step ahead (ngrp-paired waves L1-hit
//   the duplicate addresses).
// ---------------------------------------------------------------------------
__global__ __launch_bounds__(256) void gemm1_mfma(
    const float* __restrict__ x,
    const short* __restrict__ WsT, const short* __restrict__ WtT,
    const float* __restrict__ bs1, const float* __restrict__ bt1,
    short* __restrict__ r2s, short* __restrict__ r2t) {
  __shared__ __align__(16) short wlds[2][2][128 * 40];  // 40 KB
  int tid = threadIdx.x;
  int w = tid >> 6, l = tid & 63, lr = l & 15, lg = l >> 4;
  int ngrp = w >> 1, hhalf = w & 1;
  int n0 = blockIdx.x * 64 + ngrp * 32 + lr;   // rt=0 row
  int n1 = n0 + 16;                            // rt=1 row
  int b0 = n0 / CC, c0 = n0 - b0 * CC;
  int b1 = n1 / CC, c1 = n1 - b1 * CC;
  const float* xb0 = x + (size_t)b0 * (LL * CC) + c0;
  const float* xb1 = x + (size_t)b1 * (LL * CC) + c1;

  // staging: 512 16B-chunks per branch, 2 per thread per branch
  int rowA = tid >> 2, cqA = tid & 3;
  int rowB = (tid + 256) >> 2, cqB = tid & 3;
  const short* gSA = WsT + rowA * LPAD + cqA * 8;
  const short* gSB = WsT + rowB * LPAD + cqB * 8;
  const short* gTA = WtT + rowA * LPAD + cqA * 8;
  const short* gTB = WtT + rowB * LPAD + cqB * 8;
  int dA = rowA * 40 + cqA * 8;
  int dB = rowB * 40 + cqB * 8;

  f32x4 acc[2][4][2];  // [branch][ht][rt]
#pragma unroll
  for (int br = 0; br < 2; ++br)
#pragma unroll
    for (int i = 0; i < 4; ++i)
#pragma unroll
      for (int rt = 0; rt < 2; ++rt) acc[br][i][rt] = (f32x4){0.f, 0.f, 0.f, 0.f};

  // prologue: stage step 0; load x step 0
  {
    int4 sA = *(const int4*)gSA;
    int4 sB = *(const int4*)gSB;
    int4 tA = *(const int4*)gTA;
    int4 tB = *(const int4*)gTB;
    *(int4*)&wlds[0][0][dA] = sA;
    *(int4*)&wlds[0][0][dB] = sB;
    *(int4*)&wlds[0][1][dA] = tA;
    *(int4*)&wlds[0][1][dB] = tB;
  }
  float xc0[8], xc1[8];
#pragma unroll
  for (int j = 0; j < 4; ++j) {
    int k1 = lg * 4 + j, k2 = k1 + 16;
    xc0[j] = xb0[(size_t)k1 * CC];
    xc0[j + 4] = xb0[(size_t)k2 * CC];
    xc1[j] = xb1[(size_t)k1 * CC];
    xc1[j + 4] = xb1[(size_t)k2 * CC];
  }
  __syncthreads();

  int hb = hhalf * 64;
  int cur = 0;
  for (int step = 0; step < 23; ++step) {
    // next-step stage loads (reg-first) + x loads
    int4 nSA = {0, 0, 0, 0}, nSB = nSA, nTA = nSA, nTB = nSA;
    float xn0[8] = {0.f}, xn1[8] = {0.f};
    if (step < 22) {
      int ko = (step + 1) * 32;
      nSA = *(const int4*)(gSA + ko);
      nSB = *(const int4*)(gSB + ko);
      nTA = *(const int4*)(gTA + ko);
      nTB = *(const int4*)(gTB + ko);
#pragma unroll
      for (int j = 0; j < 4; ++j) {
        int k1 = ko + lg * 4 + j;   // <= 719 always
        int k2 = k1 + 16;           // may pad at last step
        bool ok = k2 < LL;
        xn0[j] = xb0[(size_t)k1 * CC];
        xn0[j + 4] = ok ? xb0[(size_t)k2 * CC] : 0.f;
        xn1[j] = xb1[(size_t)k1 * CC];
        xn1[j + 4] = ok ? xb1[(size_t)k2 * CC] : 0.f;
      }
    }

    // B-frags from current x regs
    bf16x8 bx0, bx1;
#pragma unroll
    for (int j = 0; j < 8; ++j) {
      bx0[j] = f2bf(xc0[j]);
      bx1[j] = f2bf(xc1[j]);
    }

    const short* tS = &wlds[cur][0][0];
    const short* tT = &wlds[cur][1][0];
#pragma unroll
    for (int ht = 0; ht < 4; ++ht) {
      int h = hb + ht * 16 + lr;
      bf16x8 aS = ldsfragR(tS, h, lg);
      bf16x8 aT = ldsfragR(tT, h, lg);
      acc[0][ht][0] =
          __builtin_amdgcn_mfma_f32_16x16x32_bf16(aS, bx0, acc[0][ht][0], 0, 0, 0);
      acc[0][ht][1] =
          __builtin_amdgcn_mfma_f32_16x16x32_bf16(aS, bx1, acc[0][ht][1], 0, 0, 0);
      acc[1][ht][0] =
          __builtin_amdgcn_mfma_f32_16x16x32_bf16(aT, bx0, acc[1][ht][0], 0, 0, 0);
      acc[1][ht][1] =
          __builtin_amdgcn_mfma_f32_16x16x32_bf16(aT, bx1, acc[1][ht][1], 0, 0, 0);
    }

    if (step < 22) {
      short* bS = &wlds[cur ^ 1][0][0];
      short* bT = &wlds[cur ^ 1][1][0];
      *(int4*)&bS[dA] = nSA;
      *(int4*)&bS[dB] = nSB;
      *(int4*)&bT[dA] = nTA;
      *(int4*)&bT[dB] = nTB;
    }
    __syncthreads();
#pragma unroll
    for (int j = 0; j < 8; ++j) {
      xc0[j] = xn0[j];
      xc1[j] = xn1[j];
    }
    cur ^= 1;
  }

  // epilogue: sigmoid -> bf16 R at shorts [128..255] of rows n0 and n1
#pragma unroll
  for (int rt = 0; rt < 2; ++rt) {
    int n = rt ? n1 : n0;
    short* rowS = r2s + (size_t)n * 256 + 128;
    short* rowT = r2t + (size_t)n * 256 + 128;
#pragma unroll
    for (int ht = 0; ht < 4; ++ht) {
      int h = hb + ht * 16 + lg * 4;
      float4 bS = *(const float4*)&bs1[h];
      float4 bT = *(const float4*)&bt1[h];
      const float* pbS = &bS.x;
      const float* pbT = &bT.x;
      short4 ss, st;
      short* ps = &ss.x;
      short* pt = &st.x;
#pragma unroll
      for (int j = 0; j < 4; ++j) {
        ps[j] = f2bf(1.f / (1.f + __expf(-(acc[0][ht][rt][j] + pbS[j]))));
        pt[j] = f2bf(1.f / (1.f + __expf(-(acc[1][ht][rt][j] + pbT[j]))));
      }
      *(short4*)&rowS[h] = ss;
      *(short4*)&rowT[h] = st;
    }
  }
}

// ---------------------------------------------------------------------------
// Kernel 3 (v4): pipelined MFMA memory-enhance (unchanged from round 7).
// ---------------------------------------------------------------------------
__global__ __launch_bounds__(256) void memenh_mfma(
    const short* __restrict__ stgS, const short* __restrict__ stgT,
    short* __restrict__ r2s, short* __restrict__ r2t) {
  int br = blockIdx.y;
  const short* stg = br ? stgT : stgS;
  short* r2 = br ? r2t : r2s;

  __shared__ __align__(16) short buf[2][16384];  // 64 KB
  int tid = threadIdx.x;
  int l = tid & 63, lr = l & 15, lg = l >> 4;
  int wbase = tid & 192;
  int n = blockIdx.x * 64 + (tid >> 6) * 16 + lr;

  bf16x8 brag[4];
  {
    const short* rb = r2 + (size_t)n * 256 + 128;
#pragma unroll
    for (int k = 0; k < 4; ++k) brag[k] = ldfrag(rb + k * 32 + lg * 4);
  }

#define STAGE(t, bsel)                                                        \
  {                                                                           \
    const short* g = stg + (size_t)(t)*16384;                                 \
    _Pragma("unroll") for (int i = 0; i < 8; ++i) {                           \
      gload_lds16(g + (size_t)(i * 256 + tid) * 8,                            \
                  &buf[bsel][(i * 256 + wbase) * 8]);                         \
    }                                                                         \
  }

  STAGE(0, 0);
  __syncthreads();

  f32x4 accO[8];
#pragma unroll
  for (int i = 0; i < 8; ++i) accO[i] = (f32x4){0.f, 0.f, 0.f, 0.f};
  bf16x8 pb[4];
  float ssum = 0.f;
  int cur = 0;

#pragma unroll
  for (int t = 0; t < 8; ++t) {
    if (t < 7) STAGE(t + 1, cur ^ 1);
    const short* tb = &buf[cur][0];
    if ((t & 1) == 0) {
      f32x4 sc[8];
#pragma unroll
      for (int ft16 = 0; ft16 < 8; ++ft16) {
        f32x4 a = {0.f, 0.f, 0.f, 0.f};
#pragma unroll
        for (int k = 0; k < 4; ++k) {
          int row = ft16 * 16 + lr;
          int slot = (4 * k + lg) ^ (row & 7);
          bf16x8 af = *(const bf16x8*)&tb[row * 128 + slot * 8];
          a = __builtin_amdgcn_mfma_f32_16x16x32_bf16(af, brag[k], a, 0, 0, 0);
        }
        sc[ft16] = a;
      }
#pragma unroll
      for (int i = 0; i < 8; ++i) {
        f32x4 v = sc[i];
#pragma unroll
        for (int j = 0; j < 4; ++j) {
          float e = __expf(v[j]);
          v[j] = e;
          ssum += e;
        }
        sc[i] = v;
      }
#pragma unroll
      for (int t4 = 0; t4 < 4; ++t4) {
        f32x4 e0 = sc[2 * t4], e1 = sc[2 * t4 + 1];
        bf16x8 f;
        f[0] = f2bf(e0[0]); f[1] = f2bf(e0[1]);
        f[2] = f2bf(e0[2]); f[3] = f2bf(e0[3]);
        f[4] = f2bf(e1[0]); f[5] = f2bf(e1[1]);
        f[6] = f2bf(e1[2]); f[7] = f2bf(e1[3]);
        pb[t4] = f;
      }
    } else {
#pragma unroll
      for (int dt = 0; dt < 8; ++dt) {
#pragma unroll
        for (int k = 0; k < 4; ++k) {
          int row = dt * 16 + lr;
          int slot = (4 * k + lg) ^ (row & 7);
          bf16x8 af = *(const bf16x8*)&tb[row * 128 + slot * 8];
          accO[dt] =
              __builtin_amdgcn_mfma_f32_16x16x32_bf16(af, pb[k], accO[dt], 0, 0, 0);
        }
      }
    }
    __syncthreads();
    cur ^= 1;
  }
#undef STAGE

  ssum += __shfl_xor(ssum, 16);
  ssum += __shfl_xor(ssum, 32);
  float inv = 1.f / ssum;
  short* rowO = r2 + (size_t)n * 256;
#pragma unroll
  for (int dt = 0; dt < 8; ++dt) {
    short4 o;
    o.x = f2bf(accO[dt][0] * inv);
    o.y = f2bf(accO[dt][1] * inv);
    o.z = f2bf(accO[dt][2] * inv);
    o.w = f2bf(accO[dt][3] * inv);
    *(short4*)&rowO[dt * 16 + lg * 4] = o;
  }
}

// ---------------------------------------------------------------------------
// Kernel 4: MFMA GEMM2 (bf16, K=512 concat) + bias + transposed store.
//   (unchanged)
// ---------------------------------------------------------------------------
__global__ __launch_bounds__(512) void gemm2_mfma(
    const short* __restrict__ r2s, const short* __restrict__ r2t,
    const short* __restrict__ W2b,  // [336][512] bf16
    const float* __restrict__ b2,   // [336]
    float* __restrict__ out) {
  __shared__ __align__(16) short w2lds[2][112 * 40];  // 17.9 KB
  int tid = threadIdx.x;
  int w = tid >> 6, l = tid & 63, lr = l & 15, lg = l >> 4;
  int p0 = blockIdx.y * 112;
  int n = blockIdx.x * 128 + w * 16 + lr;
  int b = n / CC, c = n - b * CC;
  const short* rs = r2s + (size_t)n * 256;
  const short* rt = r2t + (size_t)n * 256;

  bool dostage = tid < 448;
  int row = tid >> 2, q = tid & 3;
  const short* gW = W2b + (size_t)(p0 + row) * 512 + q * 4;
  int doff = row * 40 + q * 8;

  f32x4 acc[7];
#pragma unroll
  for (int i = 0; i < 7; ++i) acc[i] = (f32x4){0.f, 0.f, 0.f, 0.f};

  if (dostage) *(int4*)&w2lds[0][doff] = stage_chunk(gW);
  __syncthreads();

  int cur = 0;
  for (int step = 0; step < 16; ++step) {
    int k0 = step * 32;
    const short* rrow = ((k0 < 256) ? rs : rt) + (k0 & 255);
    bf16x8 bfr = ldfrag(rrow + lg * 4);
    int4 nxt = {0, 0, 0, 0};
    if (step < 15 && dostage) nxt = stage_chunk(gW + (step + 1) * 32);
    const short* tw = &w2lds[cur][0];
#pragma unroll
    for (int pt = 0; pt < 7; ++pt) {
      bf16x8 a = ldsfragP(tw, pt * 16 + lr, lg);
      acc[pt] = __builtin_amdgcn_mfma_f32_16x16x32_bf16(a, bfr, acc[pt], 0, 0, 0);
    }
    if (step < 15 && dostage) *(int4*)&w2lds[cur ^ 1][doff] = nxt;
    __syncthreads();
    cur ^= 1;
  }

  size_t obase = (size_t)b * ((size_t)PP * CC) + c;
#pragma unroll
  for (int pt = 0; pt < 7; ++pt) {
    int p = p0 + pt * 16 + lg * 4;
    float4 bias = *(const float4*)&b2[p];
    const float* pb = &bias.x;
#pragma unroll
    for (int j = 0; j < 4; ++j) {
      out[obase + (size_t)(p + j) * CC] = acc[pt][j] + pb[j];
    }
  }
}

// ---------------------------------------------------------------------------
extern "C" void kernel_launch(void* const* d_in, const int* in_sizes, int n_in,
                              void* d_out, int out_size, void* d_ws, size_t ws_size,
                              hipStream_t stream) {
  const float* x    = (const float*)d_in[0];
  const float* Ws1  = (const float*)d_in[1];
  const float* bs1  = (const float*)d_in[2];
  const float* Ws2  = (const float*)d_in[3];
  const float* bs2  = (const float*)d_in[4];
  const float* Wt1  = (const float*)d_in[5];
  const float* bt1  = (const float*)d_in[6];
  const float* Wt2  = (const float*)d_in[7];
  const float* bt2  = (const float*)d_in[8];
  const float* memS = (const float*)d_in[9];
  const float* memT = (const float*)d_in[10];
  float* out = (float*)d_out;

  const size_t N = (size_t)BB * CC;          // 41088
  short* r2s  = (short*)d_ws;                // [N][256] bf16: [O | R]
  short* r2t  = r2s + N * 256;
  short* WsTb = r2t + N * 256;               // [H][LPAD] bf16
  short* WtTb = WsTb + (size_t)HH * LPAD;
  short* stgS = WtTb + (size_t)HH * LPAD;    // staged mem image
  short* stgT = stgS + (size_t)16384 * 8;
  short* W2b  = stgT + (size_t)16384 * 8;    // [336][512] bf16
  float* b2   = (float*)(W2b + (size_t)PP * 512);

  // 1. precompute weights / staged conversions
  weff_kernel<<<(HH * LPAD) / 256, 256, 0, stream>>>(Ws1, Wt1, WsTb, WtTb);
  memstage_kernel<<<128, 256, 0, stream>>>(memS, memT, stgS, stgT);
  w2cvt_kernel<<<(PP * 512) / 256, 256, 0, stream>>>(Ws2, Wt2, bs2, bt2, W2b, b2);

  // 2. MFMA GEMM1 + sigmoid (both branches), grid 642
  gemm1_mfma<<<642, 256, 0, stream>>>(x, WsTb, WtTb, bs1, bt1, r2s, r2t);

  // 3. pipelined MFMA memory enhance, both branches in one dispatch
  dim3 g3(642, 2);
  memenh_mfma<<<g3, 256, 0, stream>>>(stgS, stgT, r2s, r2t);

  // 4. MFMA GEMM2 + bias + transposed store
  dim3 g2(321, 3);
  gemm2_mfma<<<g2, 512, 0, stream>>>(r2s, r2t, W2b, b2, out);
}

// Round 9
// 135.996 us; speedup vs baseline: 1.2223x; 1.2223x over previous
//
#include <hip/hip_runtime.h>
#include <math.h>

#define BB 128
#define LL 720
#define CC 321
#define HH 128
#define PP 336
#define MM 512
#define LPAD 736  // 720 padded to multiple of 32

typedef __attribute__((ext_vector_type(8))) short bf16x8;
typedef __attribute__((ext_vector_type(4))) float f32x4;

__device__ __forceinline__ short f2bf(float x) {
  unsigned u = __builtin_bit_cast(unsigned, x);
  u = (u + 0x7FFFu + ((u >> 16) & 1u)) >> 16;
  return (short)u;
}

// packed position of k-within-32-group: fragment lg*8 + half*4 + j
__device__ __forceinline__ int packpos(int kw) {
  return ((kw & 15) >> 2) * 8 + (kw >> 4) * 4 + (kw & 3);
}

// ---------------------------------------------------------------------------
// Kernel 1 (v2): smeared weights -> bf16 [H][LPAD], FRAGMENT-PACKED per
// 32-k group (pos = lg*8 + half*4 + j). gemm1 stages with direct int4 and
// reads one b128 per fragment.
// ---------------------------------------------------------------------------
__global__ void weff_kernel(const float* __restrict__ Ws1,
                            const float* __restrict__ Wt1,
                            short* __restrict__ WsT,
                            short* __restrict__ WtT) {
  int idx = blockIdx.x * 256 + threadIdx.x;
  if (idx >= HH * LPAD) return;
  int j = idx % LPAD, h = idx / LPAD;
  int t = j >> 5, kw = j & 31;
  int dst = h * LPAD + t * 32 + packpos(kw);
  if (j >= LL) { WsT[dst] = 0; WtT[dst] = 0; return; }
  float ss = 0.f, st = 0.f;
  if (j == 0) {
    for (int l = 0; l <= 12; ++l) {
      float w = 13.f - (float)l;
      ss += w * Ws1[h * LL + l];
      st += w * Wt1[h * LL + l];
    }
  } else if (j == LL - 1) {
    for (int d = 0; d <= 12; ++d) {
      float w = 13.f - (float)d;
      ss += w * Ws1[h * LL + LL - 1 - d];
      st += w * Wt1[h * LL + LL - 1 - d];
    }
  } else {
    int lo = j - 12 < 0 ? 0 : j - 12;
    int hi = j + 12 > LL - 1 ? LL - 1 : j + 12;
    for (int l = lo; l <= hi; ++l) {
      ss += Ws1[h * LL + l];
      st += Wt1[h * LL + l];
    }
  }
  ss *= (1.f / 25.f);
  st *= (1.f / 25.f);
  WsT[dst] = f2bf(Ws1[h * LL + j] - ss);
  WtT[dst] = f2bf(st);
}

// ---------------------------------------------------------------------------
// Kernel 1b: staged mem images for memenh (unchanged from round 7).
// ---------------------------------------------------------------------------
__global__ void memstage_kernel(const float* __restrict__ memS,
                                const float* __restrict__ memT,
                                short* __restrict__ stgS,
                                short* __restrict__ stgT) {
  int e = blockIdx.x * 256 + threadIdx.x;  // 0..32767
  int br = e >> 14;
  int s = e & 16383;
  const float* src = br ? memT : memS;
  short* dst = br ? stgT : stgS;
  int tt = s >> 11;                        // tile 0..7
  int c = s & 2047;
  int row = c >> 4, slot = c & 15;
  int sp = slot ^ (row & 7);
  int k = sp >> 2, lg = sp & 3;
  int ft = tt >> 1;
  short out[8];
  if ((tt & 1) == 0) {
    const float* r0 = src + (size_t)(ft * 128 + row) * 128 + k * 32 + lg * 4;
#pragma unroll
    for (int j = 0; j < 4; ++j) {
      out[j] = f2bf(r0[j]);
      out[j + 4] = f2bf(r0[16 + j]);
    }
  } else {
    int fbase = ft * 128 + k * 32 + lg * 4;
#pragma unroll
    for (int j = 0; j < 4; ++j) {
      out[j] = f2bf(src[(size_t)(fbase + j) * 128 + row]);
      out[j + 4] = f2bf(src[(size_t)(fbase + 16 + j) * 128 + row]);
    }
  }
  short4 a = make_short4(out[0], out[1], out[2], out[3]);
  short4 b = make_short4(out[4], out[5], out[6], out[7]);
  *(short4*)&dst[(size_t)s * 8] = a;
  *(short4*)&dst[(size_t)s * 8 + 4] = b;
}

// ---------------------------------------------------------------------------
// Kernel 1c (v2): W2cat bf16 [336][512], FRAGMENT-PACKED per 32-group,
// + bias sum. gemm2 stages with direct int4.
// ---------------------------------------------------------------------------
__global__ void w2cvt_kernel(const float* __restrict__ Ws2,
                             const float* __restrict__ Wt2,
                             const float* __restrict__ bs2,
                             const float* __restrict__ bt2,
                             short* __restrict__ W2b, float* __restrict__ b2) {
  int i = blockIdx.x * 256 + threadIdx.x;
  if (i < PP) b2[i] = bs2[i] + bt2[i];
  if (i >= PP * 512) return;
  int p = i >> 9, k = i & 511;
  float v = (k < 256) ? Ws2[p * 256 + k] : Wt2[p * 256 + (k - 256)];
  W2b[p * 512 + (k >> 5) * 32 + packpos(k & 31)] = f2bf(v);
}

// ---------------------------------------------------------------------------
// Kernel 2 (v5): MFMA dual-branch GEMM1 + sigmoid, coalesced x via in-block
//   LDS transpose. 256 thr / 4 waves; wave = 32 n x 64 h x 2 branches;
//   block = 64 n x 128 h; BK=32; grid 642.
//   W: packed rows, direct-int4 staged, 1 b128 read/frag.
//   x: per step a 32k x 64n slab loaded wave-coalesced (8 row-segments per
//      wave), bf16-converted in-reg, written packed (2 b64), read 1 b128.
//   Epilogue: sigmoid -> PACKED bf16 R at r2[n][128..255].
// ---------------------------------------------------------------------------
__global__ __launch_bounds__(256) void gemm1_mfma(
    const float* __restrict__ x,
    const short* __restrict__ WsT, const short* __restrict__ WtT,
    const float* __restrict__ bs1, const float* __restrict__ bt1,
    short* __restrict__ r2s, short* __restrict__ r2t) {
  __shared__ __align__(16) short wlds[2][2][128 * 40];  // 40 KB
  __shared__ __align__(16) short xlds[2][64 * 40];      // 10 KB
  int tid = threadIdx.x;
  int w = tid >> 6, l = tid & 63, lr = l & 15, lg = l >> 4;
  int ngrp = w >> 1, hhalf = w & 1, hb = hhalf * 64;
  int nb = blockIdx.x * 64;  // 41088 = 642*64 exact
  int cc0 = ngrp * 32 + lr, cc1 = cc0 + 16;
  int n0 = nb + cc0, n1 = nb + cc1;

  // W staging: 128 rows x 4 int4-chunks = 512; 2 per thread per branch
  int rowA = tid >> 2, q = tid & 3;
  int rowB = rowA + 64;
  const short* gSA = WsT + rowA * LPAD + q * 8;
  const short* gSB = WsT + rowB * LPAD + q * 8;
  const short* gTA = WtT + rowA * LPAD + q * 8;
  const short* gTB = WtT + rowB * LPAD + q * 8;
  int dA = rowA * 40 + q * 8, dB = rowB * 40 + q * 8;

  // x staging: thread = (column cc, k-group kg); 8 wave-coalesced loads
  int xcc = tid & 63, kg = tid >> 6;
  int xn = nb + xcc;
  int xb_ = xn / CC, xc_ = xn - xb_ * CC;
  const float* xptr = x + (size_t)xb_ * (LL * CC) + xc_;
  int dx0 = xcc * 40 + ((kg & 1) * 2 + 0) * 8 + (kg >> 1) * 4;  // k_w = kg*8
  int dx1 = xcc * 40 + ((kg & 1) * 2 + 1) * 8 + (kg >> 1) * 4;  // k_w = kg*8+4

  f32x4 acc[2][4][2];  // [branch][ht][rt]
#pragma unroll
  for (int br = 0; br < 2; ++br)
#pragma unroll
    for (int i = 0; i < 4; ++i)
#pragma unroll
      for (int rt = 0; rt < 2; ++rt) acc[br][i][rt] = (f32x4){0.f, 0.f, 0.f, 0.f};

  // ---- prologue: stage step 0 ----
  {
    int4 sA = *(const int4*)gSA;
    int4 sB = *(const int4*)gSB;
    int4 tA = *(const int4*)gTA;
    int4 tB = *(const int4*)gTB;
    *(int4*)&wlds[0][0][dA] = sA;
    *(int4*)&wlds[0][0][dB] = sB;
    *(int4*)&wlds[0][1][dA] = tA;
    *(int4*)&wlds[0][1][dB] = tB;
    float xf[8];
#pragma unroll
    for (int j = 0; j < 8; ++j) {
      int k = kg * 8 + j;
      xf[j] = xptr[(size_t)k * CC];
    }
    short4 s0 = make_short4(f2bf(xf[0]), f2bf(xf[1]), f2bf(xf[2]), f2bf(xf[3]));
    short4 s1 = make_short4(f2bf(xf[4]), f2bf(xf[5]), f2bf(xf[6]), f2bf(xf[7]));
    *(short4*)&xlds[0][dx0] = s0;
    *(short4*)&xlds[0][dx1] = s1;
  }
  __syncthreads();

  int cur = 0;
  for (int step = 0; step < 23; ++step) {
    // prefetch next step into regs
    int4 nSA = {0, 0, 0, 0}, nSB = nSA, nTA = nSA, nTB = nSA;
    float xf[8] = {0.f};
    if (step < 22) {
      int ko = (step + 1) * 32;
      nSA = *(const int4*)(gSA + ko);
      nSB = *(const int4*)(gSB + ko);
      nTA = *(const int4*)(gTA + ko);
      nTB = *(const int4*)(gTB + ko);
#pragma unroll
      for (int j = 0; j < 8; ++j) {
        int k = ko + kg * 8 + j;
        xf[j] = (k < LL) ? xptr[(size_t)k * CC] : 0.f;
      }
    }

    // compute current step
    const short* xl = &xlds[cur][0];
    bf16x8 bx0 = *(const bf16x8*)&xl[cc0 * 40 + lg * 8];
    bf16x8 bx1 = *(const bf16x8*)&xl[cc1 * 40 + lg * 8];
    const short* tS = &wlds[cur][0][0];
    const short* tT = &wlds[cur][1][0];
#pragma unroll
    for (int ht = 0; ht < 4; ++ht) {
      int h = hb + ht * 16 + lr;
      bf16x8 aS = *(const bf16x8*)&tS[h * 40 + lg * 8];
      bf16x8 aT = *(const bf16x8*)&tT[h * 40 + lg * 8];
      acc[0][ht][0] =
          __builtin_amdgcn_mfma_f32_16x16x32_bf16(aS, bx0, acc[0][ht][0], 0, 0, 0);
      acc[0][ht][1] =
          __builtin_amdgcn_mfma_f32_16x16x32_bf16(aS, bx1, acc[0][ht][1], 0, 0, 0);
      acc[1][ht][0] =
          __builtin_amdgcn_mfma_f32_16x16x32_bf16(aT, bx0, acc[1][ht][0], 0, 0, 0);
      acc[1][ht][1] =
          __builtin_amdgcn_mfma_f32_16x16x32_bf16(aT, bx1, acc[1][ht][1], 0, 0, 0);
    }

    // write next-step buffers
    if (step < 22) {
      short* bS = &wlds[cur ^ 1][0][0];
      short* bT = &wlds[cur ^ 1][1][0];
      *(int4*)&bS[dA] = nSA;
      *(int4*)&bS[dB] = nSB;
      *(int4*)&bT[dA] = nTA;
      *(int4*)&bT[dB] = nTB;
      short4 s0 = make_short4(f2bf(xf[0]), f2bf(xf[1]), f2bf(xf[2]), f2bf(xf[3]));
      short4 s1 = make_short4(f2bf(xf[4]), f2bf(xf[5]), f2bf(xf[6]), f2bf(xf[7]));
      *(short4*)&xlds[cur ^ 1][dx0] = s0;
      *(short4*)&xlds[cur ^ 1][dx1] = s1;
    }
    __syncthreads();
    cur ^= 1;
  }

  // epilogue: sigmoid -> PACKED bf16 R at shorts [128..255]
#pragma unroll
  for (int rt = 0; rt < 2; ++rt) {
    int n = rt ? n1 : n0;
    short* rowS = r2s + (size_t)n * 256 + 128;
    short* rowT = r2t + (size_t)n * 256 + 128;
#pragma unroll
    for (int ht = 0; ht < 4; ++ht) {
      int h = hb + ht * 16 + lg * 4;           // actual h of elems j=0..3
      int hbase = hb + ht * 16;
      int dst = (hbase >> 5) * 32 + lg * 8 + ((hbase >> 4) & 1) * 4;
      float4 bS = *(const float4*)&bs1[h];
      float4 bT = *(const float4*)&bt1[h];
      const float* pbS = &bS.x;
      const float* pbT = &bT.x;
      short4 ss, st;
      short* ps = &ss.x;
      short* pt = &st.x;
#pragma unroll
      for (int j = 0; j < 4; ++j) {
        ps[j] = f2bf(1.f / (1.f + __expf(-(acc[0][ht][rt][j] + pbS[j]))));
        pt[j] = f2bf(1.f / (1.f + __expf(-(acc[1][ht][rt][j] + pbT[j]))));
      }
      *(short4*)&rowS[dst] = ss;
      *(short4*)&rowT[dst] = st;
    }
  }
}

// ---------------------------------------------------------------------------
// Kernel 3 (v5): pipelined MFMA memory-enhance. Same as round 7 except:
//   R-frags read as single b128 (R is packed), O written PACKED.
// ---------------------------------------------------------------------------
__global__ __launch_bounds__(256) void memenh_mfma(
    const short* __restrict__ stgS, const short* __restrict__ stgT,
    short* __restrict__ r2s, short* __restrict__ r2t) {
  int br = blockIdx.y;
  const short* stg = br ? stgT : stgS;
  short* r2 = br ? r2t : r2s;

  __shared__ __align__(16) short buf[2][16384];  // 64 KB
  int tid = threadIdx.x;
  int l = tid & 63, lr = l & 15, lg = l >> 4;
  int wbase = tid & 192;
  int n = blockIdx.x * 64 + (tid >> 6) * 16 + lr;

  bf16x8 brag[4];
  {
    const short* rb = r2 + (size_t)n * 256 + 128;
#pragma unroll
    for (int k = 0; k < 4; ++k)
      brag[k] = *(const bf16x8*)&rb[k * 32 + lg * 8];
  }

#define STAGE(t, bsel)                                                        \
  {                                                                           \
    const short* g = stg + (size_t)(t)*16384;                                 \
    _Pragma("unroll") for (int i = 0; i < 8; ++i) {                           \
      __builtin_amdgcn_global_load_lds(                                       \
          (const __attribute__((address_space(1))) unsigned int*)(            \
              g + (size_t)(i * 256 + tid) * 8),                               \
          (__attribute__((address_space(3))) unsigned int*)(                  \
              &buf[bsel][(i * 256 + wbase) * 8]),                             \
          16, 0, 0);                                                          \
    }                                                                         \
  }

  STAGE(0, 0);
  __syncthreads();

  f32x4 accO[8];
#pragma unroll
  for (int i = 0; i < 8; ++i) accO[i] = (f32x4){0.f, 0.f, 0.f, 0.f};
  bf16x8 pb[4];
  float ssum = 0.f;
  int cur = 0;

#pragma unroll
  for (int t = 0; t < 8; ++t) {
    if (t < 7) STAGE(t + 1, cur ^ 1);
    const short* tb = &buf[cur][0];
    if ((t & 1) == 0) {
      f32x4 sc[8];
#pragma unroll
      for (int ft16 = 0; ft16 < 8; ++ft16) {
        f32x4 a = {0.f, 0.f, 0.f, 0.f};
#pragma unroll
        for (int k = 0; k < 4; ++k) {
          int row = ft16 * 16 + lr;
          int slot = (4 * k + lg) ^ (row & 7);
          bf16x8 af = *(const bf16x8*)&tb[row * 128 + slot * 8];
          a = __builtin_amdgcn_mfma_f32_16x16x32_bf16(af, brag[k], a, 0, 0, 0);
        }
        sc[ft16] = a;
      }
#pragma unroll
      for (int i = 0; i < 8; ++i) {
        f32x4 v = sc[i];
#pragma unroll
        for (int j = 0; j < 4; ++j) {
          float e = __expf(v[j]);
          v[j] = e;
          ssum += e;
        }
        sc[i] = v;
      }
#pragma unroll
      for (int t4 = 0; t4 < 4; ++t4) {
        f32x4 e0 = sc[2 * t4], e1 = sc[2 * t4 + 1];
        bf16x8 f;
        f[0] = f2bf(e0[0]); f[1] = f2bf(e0[1]);
        f[2] = f2bf(e0[2]); f[3] = f2bf(e0[3]);
        f[4] = f2bf(e1[0]); f[5] = f2bf(e1[1]);
        f[6] = f2bf(e1[2]); f[7] = f2bf(e1[3]);
        pb[t4] = f;
      }
    } else {
#pragma unroll
      for (int dt = 0; dt < 8; ++dt) {
#pragma unroll
        for (int k = 0; k < 4; ++k) {
          int row = dt * 16 + lr;
          int slot = (4 * k + lg) ^ (row & 7);
          bf16x8 af = *(const bf16x8*)&tb[row * 128 + slot * 8];
          accO[dt] =
              __builtin_amdgcn_mfma_f32_16x16x32_bf16(af, pb[k], accO[dt], 0, 0, 0);
        }
      }
    }
    __syncthreads();
    cur ^= 1;
  }
#undef STAGE

  ssum += __shfl_xor(ssum, 16);
  ssum += __shfl_xor(ssum, 32);
  float inv = 1.f / ssum;
  short* rowO = r2 + (size_t)n * 256;
#pragma unroll
  for (int dt = 0; dt < 8; ++dt) {
    short4 o;
    o.x = f2bf(accO[dt][0] * inv);
    o.y = f2bf(accO[dt][1] * inv);
    o.z = f2bf(accO[dt][2] * inv);
    o.w = f2bf(accO[dt][3] * inv);
    // packed position: group dt>>1, lane-frag lg, half dt&1
    *(short4*)&rowO[(dt >> 1) * 32 + lg * 8 + (dt & 1) * 4] = o;
  }
}

// ---------------------------------------------------------------------------
// Kernel 4 (v2): MFMA GEMM2 (bf16, K=512 concat, packed operands) + bias +
//   transposed store. W2 staged via direct int4 (packed source).
// ---------------------------------------------------------------------------
__global__ __launch_bounds__(512) void gemm2_mfma(
    const short* __restrict__ r2s, const short* __restrict__ r2t,
    const short* __restrict__ W2b,  // [336][512] bf16 packed
    const float* __restrict__ b2,   // [336]
    float* __restrict__ out) {
  __shared__ __align__(16) short w2lds[2][112 * 40];  // 17.9 KB
  int tid = threadIdx.x;
  int w = tid >> 6, l = tid & 63, lr = l & 15, lg = l >> 4;
  int p0 = blockIdx.y * 112;
  int n = blockIdx.x * 128 + w * 16 + lr;
  int b = n / CC, c = n - b * CC;
  const short* rs = r2s + (size_t)n * 256;
  const short* rt = r2t + (size_t)n * 256;

  bool dostage = tid < 448;
  int row = tid >> 2, q = tid & 3;
  const short* gW = W2b + (size_t)(p0 + row) * 512 + q * 8;
  int doff = row * 40 + q * 8;

  f32x4 acc[7];
#pragma unroll
  for (int i = 0; i < 7; ++i) acc[i] = (f32x4){0.f, 0.f, 0.f, 0.f};

  if (dostage) *(int4*)&w2lds[0][doff] = *(const int4*)gW;
  __syncthreads();

  int cur = 0;
  for (int step = 0; step < 16; ++step) {
    int k0 = step * 32;
    const short* rrow = ((k0 < 256) ? rs : rt) + (k0 & 255);
    bf16x8 bfr = *(const bf16x8*)&rrow[lg * 8];
    int4 nxt = {0, 0, 0, 0};
    if (step < 15 && dostage) nxt = *(const int4*)(gW + (step + 1) * 32);
    const short* tw = &w2lds[cur][0];
#pragma unroll
    for (int pt = 0; pt < 7; ++pt) {
      bf16x8 a = *(const bf16x8*)&tw[(pt * 16 + lr) * 40 + lg * 8];
      acc[pt] = __builtin_amdgcn_mfma_f32_16x16x32_bf16(a, bfr, acc[pt], 0, 0, 0);
    }
    if (step < 15 && dostage) *(int4*)&w2lds[cur ^ 1][doff] = nxt;
    __syncthreads();
    cur ^= 1;
  }

  size_t obase = (size_t)b * ((size_t)PP * CC) + c;
#pragma unroll
  for (int pt = 0; pt < 7; ++pt) {
    int p = p0 + pt * 16 + lg * 4;
    float4 bias = *(const float4*)&b2[p];
    const float* pb = &bias.x;
#pragma unroll
    for (int j = 0; j < 4; ++j) {
      out[obase + (size_t)(p + j) * CC] = acc[pt][j] + pb[j];
    }
  }
}

// ---------------------------------------------------------------------------
extern "C" void kernel_launch(void* const* d_in, const int* in_sizes, int n_in,
                              void* d_out, int out_size, void* d_ws, size_t ws_size,
                              hipStream_t stream) {
  const float* x    = (const float*)d_in[0];
  const float* Ws1  = (const float*)d_in[1];
  const float* bs1  = (const float*)d_in[2];
  const float* Ws2  = (const float*)d_in[3];
  const float* bs2  = (const float*)d_in[4];
  const float* Wt1  = (const float*)d_in[5];
  const float* bt1  = (const float*)d_in[6];
  const float* Wt2  = (const float*)d_in[7];
  const float* bt2  = (const float*)d_in[8];
  const float* memS = (const float*)d_in[9];
  const float* memT = (const float*)d_in[10];
  float* out = (float*)d_out;

  const size_t N = (size_t)BB * CC;          // 41088
  short* r2s  = (short*)d_ws;                // [N][256] bf16 packed: [O | R]
  short* r2t  = r2s + N * 256;
  short* WsTb = r2t + N * 256;               // [H][LPAD] bf16 packed
  short* WtTb = WsTb + (size_t)HH * LPAD;
  short* stgS = WtTb + (size_t)HH * LPAD;    // staged mem image
  short* stgT = stgS + (size_t)16384 * 8;
  short* W2b  = stgT + (size_t)16384 * 8;    // [336][512] bf16 packed
  float* b2   = (float*)(W2b + (size_t)PP * 512);

  // 1. precompute weights / staged conversions
  weff_kernel<<<(HH * LPAD) / 256, 256, 0, stream>>>(Ws1, Wt1, WsTb, WtTb);
  memstage_kernel<<<128, 256, 0, stream>>>(memS, memT, stgS, stgT);
  w2cvt_kernel<<<(PP * 512) / 256, 256, 0, stream>>>(Ws2, Wt2, bs2, bt2, W2b, b2);

  // 2. MFMA GEMM1 + sigmoid (both branches), grid 642
  gemm1_mfma<<<642, 256, 0, stream>>>(x, WsTb, WtTb, bs1, bt1, r2s, r2t);

  // 3. pipelined MFMA memory enhance, both branches in one dispatch
  dim3 g3(642, 2);
  memenh_mfma<<<g3, 256, 0, stream>>>(stgS, stgT, r2s, r2t);

  // 4. MFMA GEMM2 + bias + transposed store
  dim3 g2(321, 3);
  gemm2_mfma<<<g2, 512, 0, stream>>>(r2s, r2t, W2b, b2, out);
}